// Round 2
// baseline (271.442 us; speedup 1.0000x reference)
//
#include <hip/hip_runtime.h>
#include <math.h>

#define RBINS 160
#define BROWS 65536
#define ROWELEMS 480                    // 160 bins * 3 channels
#define ROWF4 (ROWELEMS / 4)            // 120
#define TASKS_PER_ROW 40                // each task: 4 bins x 3 ch = 12 elements
#define NTHREADS 256
#define NBLOCKS_MAIN ((BROWS * TASKS_PER_ROW) / NTHREADS)   // 10240
#define CFIX 8                          // fixup region: c in [0, CFIX)
#define NBLOCKS_FIX 512
#define FIXTHREADS (NBLOCKS_FIX * NTHREADS)                 // 131072
#define FIXITERS ((BROWS * CFIX) / FIXTHREADS)              // 4

__device__ __forceinline__ float clamp01(float x) {
    return __builtin_amdgcn_fmed3f(x, 0.0f, 1.0f);
}

// 12-output 4-tap stencil over a 24-float register window. P (wave-uniform
// misalignment 0..3) is a template arg so every w[] index is compile-time
// (rule #20: runtime-indexed arrays go to scratch).
template<int P>
__device__ __forceinline__ void stencil12(
    const float* __restrict__ w,
    float u1, float u2, float u3, float u4,
    float* __restrict__ r)
{
    #pragma unroll
    for (int m = 0; m < 12; ++m) {
        float acc = u1 * w[P + m];
        acc = fmaf(u2, w[P + m + 3], acc);
        acc = fmaf(u3, w[P + m + 6], acc);
        acc = fmaf(u4, w[P + m + 9], acc);
        r[m] = acc;
    }
}

// Injection of the 5-bin spread kernel into window elements with f in [0,15).
__device__ __forceinline__ void inject24(
    float* __restrict__ w, int a0,
    const float* __restrict__ color, int b,
    float aw0, float aw1, float aw2, float aw3, float aw4)
{
    const float c0 = color[3*b+0];
    const float c1 = color[3*b+1];
    const float c2 = color[3*b+2];
    #pragma unroll
    for (int u = 0; u < 24; ++u) {
        const int f = a0 + u;
        if ((unsigned)f < 15u) {
            const int bin = f / 3;            // f >= 0 here
            const int ch  = f - 3 * bin;
            const float cv = (ch == 0) ? c0 : (ch == 1) ? c1 : c2;
            const float av = (bin == 0) ? aw0 : (bin == 1) ? aw1 :
                             (bin == 2) ? aw2 : (bin == 3) ? aw3 : aw4;
            w[u] += cv * av;
        }
    }
}

__global__ __launch_bounds__(NTHREADS, 8) void beat_kernel(
    const float* __restrict__ hist,
    const float* __restrict__ color,
    const float* __restrict__ p_offset,
    const float* __restrict__ p_persist,
    const float* __restrict__ p_diff,
    const float* __restrict__ p_dt,
    const float* __restrict__ p_amount,
    const float* __restrict__ p_spread,
    float* __restrict__ out)
{
    // ---- wave-uniform parameter math (mirrors ref f32 ops) ----
    const float offs = *p_offset;
    const float pers = *p_persist;
    const float diff = *p_diff;
    const float dts  = *p_dt;

    const float dt       = fminf(fmaxf(dts, 0.0f), 0.05f);
    const float dt_scale = dt * 60.0f;
    const float s        = offs * dt_scale;
    const float dt_pers  = __powf(pers, dt_scale);
    const int   dfl      = (int)floorf(s);
    const float frac     = s - (float)dfl;    // uniform: floor(i+s)=i+dfl interior
    const float kk = 0.15f * diff;
    const float cc = 1.0f - 2.0f * kk;
    const float wl = (1.0f - frac) * dt_pers;
    const float wr = frac * dt_pers;
    // interior 4-tap coefficients (taps t=1..4; t=0,5 identically zero)
    const float u1 = wr * kk;
    const float u2 = fmaf(wl, kk, wr * cc);
    const float u3 = fmaf(wl, cc, wr * kk);
    const float u4 = wl * kk;

    // valid source range as element range [flo, fhi)
    const int ilo = max(0, (int)ceilf(-s));
    const int ihi = min(RBINS - 1, (int)ceilf((float)(RBINS - 1) - s) - 1);
    const int flo = 3 * ilo;
    const int fhi = 3 * ihi + 3;

    if (blockIdx.x < NBLOCKS_MAIN) {
        // ================= main region: no injection =================
        const int task = blockIdx.x * NTHREADS + threadIdx.x;
        const int b = task / TASKS_PER_ROW;
        const int c = task - b * TASKS_PER_ROW;
        const int e0 = c * 12;
        const int A  = e0 - 6 - 3 * dfl;      // first tap element
        const int p  = A & 3;                 // wave-uniform (dfl-only)
        const int a0 = A - p;                 // aligned window start
        if (A < 15 && c < CFIX) return;       // fixup blocks own these

        const float4* src4 = (const float4*)hist + (size_t)b * ROWF4;
        float w[24];
        const int q0 = a0 >> 2;
        #pragma unroll
        for (int q = 0; q < 6; ++q) {
            const int idx = min(max(q0 + q, 0), ROWF4 - 1);  // clamped quads are masked below
            const float4 v = src4[idx];
            w[4*q+0] = v.x; w[4*q+1] = v.y; w[4*q+2] = v.z; w[4*q+3] = v.w;
        }

        if (A < 15) {
            // only reachable for extreme dfl (>~25) where c>=CFIX windows touch
            // f<15; never taken on sane inputs, kept for correctness.
            const float am = fminf(fmaxf(*p_amount, 0.0f), 1.0f);
            const float sp = fminf(fmaxf(*p_spread, 0.0f), 1.0f);
            const float tight = 1.0f - sp;
            inject24(w, a0, color, b,
                     am * fmaf(0.4f, tight, 0.5f), am * fmaf(0.2f, sp, 0.05f),
                     am * (0.12f * sp), am * (0.06f * sp), am * (0.02f * sp));
        }

        // mask (valid source range) + clamp01; u is compile-time per element
        const int lo_u = flo - a0;
        const int hi_u = fhi - a0;
        #pragma unroll
        for (int u = 0; u < 24; ++u) {
            const bool v = (u >= lo_u) && (u < hi_u);
            w[u] = v ? clamp01(w[u]) : 0.0f;
        }

        float r[12];
        switch (p) {
            case 0:  stencil12<0>(w, u1, u2, u3, u4, r); break;
            case 1:  stencil12<1>(w, u1, u2, u3, u4, r); break;
            case 2:  stencil12<2>(w, u1, u2, u3, u4, r); break;
            default: stencil12<3>(w, u1, u2, u3, u4, r); break;
        }

        if (c >= TASKS_PER_ROW - 2) {          // edge fade, bins >= 152
            const int j0 = 4 * c;
            #pragma unroll
            for (int mb = 0; mb < 4; ++mb) {
                const int j = j0 + mb;
                const float t = (float)(RBINS - 1 - j) * 0.125f;
                const float ff = (j >= RBINS - 8) ? t * t : 1.0f;
                r[3*mb+0] *= ff; r[3*mb+1] *= ff; r[3*mb+2] *= ff;
            }
        }

        float4* dst = (float4*)(out + (size_t)b * ROWELEMS + e0);
        dst[0] = make_float4(r[0], r[1], r[2],  r[3]);
        dst[1] = make_float4(r[4], r[5], r[6],  r[7]);
        dst[2] = make_float4(r[8], r[9], r[10], r[11]);
    } else {
        // ================= fixup region: c in [0, CFIX), with injection =================
        const int fixtid = (blockIdx.x - NBLOCKS_MAIN) * NTHREADS + threadIdx.x;

        const float am = fminf(fmaxf(*p_amount, 0.0f), 1.0f);
        const float sp = fminf(fmaxf(*p_spread, 0.0f), 1.0f);
        const float tight = 1.0f - sp;
        const float aw0 = am * fmaf(0.4f, tight, 0.5f);
        const float aw1 = am * fmaf(0.2f, sp, 0.05f);
        const float aw2 = am * (0.12f * sp);
        const float aw3 = am * (0.06f * sp);
        const float aw4 = am * (0.02f * sp);

        #pragma unroll 1
        for (int k = 0; k < FIXITERS; ++k) {
            const int t = fixtid + k * FIXTHREADS;
            const int b = t >> 3;               // CFIX == 8
            const int c = t & (CFIX - 1);
            const int e0 = c * 12;
            const int A  = e0 - 6 - 3 * dfl;
            const int p  = A & 3;
            const int a0 = A - p;

            const float4* src4 = (const float4*)hist + (size_t)b * ROWF4;
            float w[24];
            const int q0 = a0 >> 2;
            #pragma unroll
            for (int q = 0; q < 6; ++q) {
                const int idx = min(max(q0 + q, 0), ROWF4 - 1);
                const float4 v = src4[idx];
                w[4*q+0] = v.x; w[4*q+1] = v.y; w[4*q+2] = v.z; w[4*q+3] = v.w;
            }

            if (A < 15)
                inject24(w, a0, color, b, aw0, aw1, aw2, aw3, aw4);

            const int lo_u = flo - a0;
            const int hi_u = fhi - a0;
            #pragma unroll
            for (int u = 0; u < 24; ++u) {
                const bool v = (u >= lo_u) && (u < hi_u);
                w[u] = v ? clamp01(w[u]) : 0.0f;
            }

            float r[12];
            switch (p) {
                case 0:  stencil12<0>(w, u1, u2, u3, u4, r); break;
                case 1:  stencil12<1>(w, u1, u2, u3, u4, r); break;
                case 2:  stencil12<2>(w, u1, u2, u3, u4, r); break;
                default: stencil12<3>(w, u1, u2, u3, u4, r); break;
            }

            if (A < 15) {                        // exact complement of main's skip
                float4* dst = (float4*)(out + (size_t)b * ROWELEMS + e0);
                dst[0] = make_float4(r[0], r[1], r[2],  r[3]);
                dst[1] = make_float4(r[4], r[5], r[6],  r[7]);
                dst[2] = make_float4(r[8], r[9], r[10], r[11]);
            }
        }
    }
}

extern "C" void kernel_launch(void* const* d_in, const int* in_sizes, int n_in,
                              void* d_out, int out_size, void* d_ws, size_t ws_size,
                              hipStream_t stream) {
    const float* hist      = (const float*)d_in[0];
    const float* color     = (const float*)d_in[1];
    const float* p_offset  = (const float*)d_in[2];
    const float* p_persist = (const float*)d_in[3];
    const float* p_diff    = (const float*)d_in[4];
    const float* p_dt      = (const float*)d_in[5];
    const float* p_amount  = (const float*)d_in[6];
    const float* p_spread  = (const float*)d_in[7];
    float* outp = (float*)d_out;

    beat_kernel<<<dim3(NBLOCKS_MAIN + NBLOCKS_FIX), dim3(NTHREADS), 0, stream>>>(
        hist, color, p_offset, p_persist, p_diff, p_dt, p_amount, p_spread, outp);
}

// Round 3
// 251.230 us; speedup vs baseline: 1.0805x; 1.0805x over previous
//
#include <hip/hip_runtime.h>
#include <math.h>

#define RBINS 160
#define BROWS 65536
#define ROWELEMS 480                    // 160 bins * 3 channels
#define ROWF4 (ROWELEMS / 4)            // 120
#define TASKS_PER_ROW 40                // each task: 4 bins x 3 ch = 12 elements
#define NTHREADS 256
#define NBLOCKS_MAIN ((BROWS * TASKS_PER_ROW) / NTHREADS)   // 10240
#define CFIX 2                          // fixup region: c in [0, CFIX)
#define NBLOCKS_FIX ((BROWS * CFIX) / NTHREADS)             // 512

__device__ __forceinline__ float clamp01(float x) {
    return __builtin_amdgcn_fmed3f(x, 0.0f, 1.0f);
}

// 12-output 4-tap stencil over a 24-float register window. P (wave-uniform
// misalignment 0..3) is a template arg so every w[] index is compile-time
// (rule #20: runtime-indexed arrays go to scratch).
template<int P>
__device__ __forceinline__ void stencil12(
    const float* __restrict__ w,
    float u1, float u2, float u3, float u4,
    float* __restrict__ r)
{
    #pragma unroll
    for (int m = 0; m < 12; ++m) {
        float acc = u1 * w[P + m];
        acc = fmaf(u2, w[P + m + 3], acc);
        acc = fmaf(u3, w[P + m + 6], acc);
        acc = fmaf(u4, w[P + m + 9], acc);
        r[m] = acc;
    }
}

// Injection of the 5-bin spread kernel into window elements with f in [0,15).
__device__ __forceinline__ void inject24(
    float* __restrict__ w, int a0,
    const float* __restrict__ color, int b,
    float aw0, float aw1, float aw2, float aw3, float aw4)
{
    const float c0 = color[3*b+0];
    const float c1 = color[3*b+1];
    const float c2 = color[3*b+2];
    #pragma unroll
    for (int u = 0; u < 24; ++u) {
        const int f = a0 + u;
        if ((unsigned)f < 15u) {
            const int bin = f / 3;            // f >= 0 here
            const int ch  = f - 3 * bin;
            const float cv = (ch == 0) ? c0 : (ch == 1) ? c1 : c2;
            const float av = (bin == 0) ? aw0 : (bin == 1) ? aw1 :
                             (bin == 2) ? aw2 : (bin == 3) ? aw3 : aw4;
            w[u] += cv * av;
        }
    }
}

__global__ __launch_bounds__(NTHREADS, 4) void beat_kernel(
    const float* __restrict__ hist,
    const float* __restrict__ color,
    const float* __restrict__ p_offset,
    const float* __restrict__ p_persist,
    const float* __restrict__ p_diff,
    const float* __restrict__ p_dt,
    const float* __restrict__ p_amount,
    const float* __restrict__ p_spread,
    float* __restrict__ out)
{
    // ---- wave-uniform parameter math (mirrors ref f32 ops) ----
    const float offs = *p_offset;
    const float pers = *p_persist;
    const float diff = *p_diff;
    const float dts  = *p_dt;

    const float dt       = fminf(fmaxf(dts, 0.0f), 0.05f);
    const float dt_scale = dt * 60.0f;
    const float s        = offs * dt_scale;
    const float dt_pers  = __powf(pers, dt_scale);
    const int   dfl      = (int)floorf(s);
    const float frac     = s - (float)dfl;    // uniform: floor(i+s)=i+dfl interior
    const float kk = 0.15f * diff;
    const float cc = 1.0f - 2.0f * kk;
    const float wl = (1.0f - frac) * dt_pers;
    const float wr = frac * dt_pers;
    // interior 4-tap coefficients (taps t=1..4; t=0,5 identically zero)
    const float u1 = wr * kk;
    const float u2 = fmaf(wl, kk, wr * cc);
    const float u3 = fmaf(wl, cc, wr * kk);
    const float u4 = wl * kk;

    // valid source range as element range [flo, fhi)
    const int ilo = max(0, (int)ceilf(-s));
    const int ihi = min(RBINS - 1, (int)ceilf((float)(RBINS - 1) - s) - 1);
    const int flo = 3 * ilo;
    const int fhi = 3 * ihi + 3;

    if (blockIdx.x < NBLOCKS_MAIN) {
        // ================= main region: no injection =================
        const int task = blockIdx.x * NTHREADS + threadIdx.x;
        const int b = task / TASKS_PER_ROW;
        const int c = task - b * TASKS_PER_ROW;
        const int e0 = c * 12;
        const int A  = e0 - 6 - 3 * dfl;      // first tap element
        const int p  = A & 3;                 // wave-uniform (dfl-only)
        const int a0 = A - p;                 // aligned window start
        if (A < 15 && c < CFIX) return;       // fixup blocks own these

        const float4* src4 = (const float4*)hist + (size_t)b * ROWF4;
        float w[24];
        const int q0 = a0 >> 2;
        #pragma unroll
        for (int q = 0; q < 6; ++q) {
            const int idx = min(max(q0 + q, 0), ROWF4 - 1);  // clamped quads are masked below
            const float4 v = src4[idx];
            w[4*q+0] = v.x; w[4*q+1] = v.y; w[4*q+2] = v.z; w[4*q+3] = v.w;
        }

        if (A < 15) {
            // only reachable for extreme dfl where c>=CFIX windows touch f<15;
            // never taken on sane inputs, kept for correctness.
            const float am = fminf(fmaxf(*p_amount, 0.0f), 1.0f);
            const float sp = fminf(fmaxf(*p_spread, 0.0f), 1.0f);
            const float tight = 1.0f - sp;
            inject24(w, a0, color, b,
                     am * fmaf(0.4f, tight, 0.5f), am * fmaf(0.2f, sp, 0.05f),
                     am * (0.12f * sp), am * (0.06f * sp), am * (0.02f * sp));
        }

        // mask (valid source range) + clamp01; u is compile-time per element
        const int lo_u = flo - a0;
        const int hi_u = fhi - a0;
        #pragma unroll
        for (int u = 0; u < 24; ++u) {
            const bool v = (u >= lo_u) && (u < hi_u);
            w[u] = v ? clamp01(w[u]) : 0.0f;
        }

        float r[12];
        switch (p) {
            case 0:  stencil12<0>(w, u1, u2, u3, u4, r); break;
            case 1:  stencil12<1>(w, u1, u2, u3, u4, r); break;
            case 2:  stencil12<2>(w, u1, u2, u3, u4, r); break;
            default: stencil12<3>(w, u1, u2, u3, u4, r); break;
        }

        if (c >= TASKS_PER_ROW - 2) {          // edge fade, bins >= 152
            const int j0 = 4 * c;
            #pragma unroll
            for (int mb = 0; mb < 4; ++mb) {
                const int j = j0 + mb;
                const float t = (float)(RBINS - 1 - j) * 0.125f;
                const float ff = (j >= RBINS - 8) ? t * t : 1.0f;
                r[3*mb+0] *= ff; r[3*mb+1] *= ff; r[3*mb+2] *= ff;
            }
        }

        float4* dst = (float4*)(out + (size_t)b * ROWELEMS + e0);
        dst[0] = make_float4(r[0], r[1], r[2],  r[3]);
        dst[1] = make_float4(r[4], r[5], r[6],  r[7]);
        dst[2] = make_float4(r[8], r[9], r[10], r[11]);
    } else {
        // ============ fixup region: c in {0,1}, with injection ============
        const int t = (blockIdx.x - NBLOCKS_MAIN) * NTHREADS + threadIdx.x;
        const int b = t >> 1;                 // CFIX == 2
        const int c = t & (CFIX - 1);
        const int e0 = c * 12;
        const int A  = e0 - 6 - 3 * dfl;
        const int p  = A & 3;
        const int a0 = A - p;

        const float4* src4 = (const float4*)hist + (size_t)b * ROWF4;
        float w[24];
        const int q0 = a0 >> 2;
        #pragma unroll
        for (int q = 0; q < 6; ++q) {
            const int idx = min(max(q0 + q, 0), ROWF4 - 1);
            const float4 v = src4[idx];
            w[4*q+0] = v.x; w[4*q+1] = v.y; w[4*q+2] = v.z; w[4*q+3] = v.w;
        }

        if (A < 15) {
            const float am = fminf(fmaxf(*p_amount, 0.0f), 1.0f);
            const float sp = fminf(fmaxf(*p_spread, 0.0f), 1.0f);
            const float tight = 1.0f - sp;
            inject24(w, a0, color, b,
                     am * fmaf(0.4f, tight, 0.5f), am * fmaf(0.2f, sp, 0.05f),
                     am * (0.12f * sp), am * (0.06f * sp), am * (0.02f * sp));
        }

        const int lo_u = flo - a0;
        const int hi_u = fhi - a0;
        #pragma unroll
        for (int u = 0; u < 24; ++u) {
            const bool v = (u >= lo_u) && (u < hi_u);
            w[u] = v ? clamp01(w[u]) : 0.0f;
        }

        float r[12];
        switch (p) {
            case 0:  stencil12<0>(w, u1, u2, u3, u4, r); break;
            case 1:  stencil12<1>(w, u1, u2, u3, u4, r); break;
            case 2:  stencil12<2>(w, u1, u2, u3, u4, r); break;
            default: stencil12<3>(w, u1, u2, u3, u4, r); break;
        }

        if (A < 15) {                          // exact complement of main's skip
            float4* dst = (float4*)(out + (size_t)b * ROWELEMS + e0);
            dst[0] = make_float4(r[0], r[1], r[2],  r[3]);
            dst[1] = make_float4(r[4], r[5], r[6],  r[7]);
            dst[2] = make_float4(r[8], r[9], r[10], r[11]);
        }
    }
}

extern "C" void kernel_launch(void* const* d_in, const int* in_sizes, int n_in,
                              void* d_out, int out_size, void* d_ws, size_t ws_size,
                              hipStream_t stream) {
    const float* hist      = (const float*)d_in[0];
    const float* color     = (const float*)d_in[1];
    const float* p_offset  = (const float*)d_in[2];
    const float* p_persist = (const float*)d_in[3];
    const float* p_diff    = (const float*)d_in[4];
    const float* p_dt      = (const float*)d_in[5];
    const float* p_amount  = (const float*)d_in[6];
    const float* p_spread  = (const float*)d_in[7];
    float* outp = (float*)d_out;

    beat_kernel<<<dim3(NBLOCKS_MAIN + NBLOCKS_FIX), dim3(NTHREADS), 0, stream>>>(
        hist, color, p_offset, p_persist, p_diff, p_dt, p_amount, p_spread, outp);
}